// Round 3
// baseline (2775.377 us; speedup 1.0000x reference)
//
#include <hip/hip_runtime.h>

constexpr int N = 50000;
constexpr int E = 1200000;
constexpr int G = 512;
constexpr int TILES = E / 64;        // 18750 exactly
constexpr float LOG2_ = 0.69314718055994531f;
constexpr float PIC = 0.39269908169872414f;   // pi / 8.0

typedef __attribute__((ext_vector_type(8))) short s8;     // 8 bf16 (4 VGPR)
typedef __attribute__((ext_vector_type(4))) float f32x4;  // MFMA acc

__device__ __forceinline__ float sspf(float x) {
    return fmaxf(x, 0.f) + __logf(1.f + __expf(-fabsf(x))) - LOG2_;
}
__device__ __forceinline__ void uadd(float* p, float v) { unsafeAtomicAdd(p, v); }
__device__ __forceinline__ ushort bf16rne(float x) {
    unsigned u = __float_as_uint(x);
    return (ushort)((u + 0x7FFFu + ((u >> 16) & 1u)) >> 16);
}
__device__ __forceinline__ float bf2f(ushort h) {
    return __uint_as_float(((unsigned)h) << 16);
}

// ---------------- sort stage 1: histogram of dst ----------------
__global__ __launch_bounds__(256) void k_hist(const int* __restrict__ eidx,
                                              int* __restrict__ cnt) {
    for (int e = blockIdx.x * 256 + threadIdx.x; e < E; e += gridDim.x * 256)
        atomicAdd(cnt + eidx[E + e], 1);
}

// ---------------- sort stage 2: exclusive scan -> cursor ----------------
__global__ __launch_bounds__(1024) void k_scan(const int* __restrict__ cnt,
                                               int* __restrict__ cursor) {
    __shared__ int part[1024];
    const int CH = 49;
    int t = threadIdx.x;
    int b = t * CH;
    int s = 0;
    for (int i = 0; i < CH; i++) { int idx = b + i; if (idx < N) s += cnt[idx]; }
    part[t] = s;
    __syncthreads();
    for (int off = 1; off < 1024; off <<= 1) {
        int add = (t >= off) ? part[t - off] : 0;
        int v = part[t];
        __syncthreads();
        part[t] = v + add;
        __syncthreads();
    }
    int excl = (t == 0) ? 0 : part[t - 1];
    for (int i = 0; i < CH; i++) {
        int idx = b + i;
        if (idx < N) { cursor[idx] = excl; excl += cnt[idx]; }
    }
}

// ---------------- sort stage 3: scatter permutation ----------------
__global__ __launch_bounds__(256) void k_scatter(const int* __restrict__ eidx,
                                                 int* __restrict__ cursor,
                                                 int* __restrict__ order) {
    for (int e = blockIdx.x * 256 + threadIdx.x; e < E; e += gridDim.x * 256) {
        int d = eidx[E + e];
        int p = atomicAdd(cursor + d, 1);
        order[p] = e;
    }
}

// ---------------- sorted meta arrays ----------------
__global__ __launch_bounds__(256) void k_meta(const int* __restrict__ eidx,
                                              const float* __restrict__ ew,
                                              const int* __restrict__ order,
                                              int* __restrict__ srcs,
                                              int* __restrict__ dsts,
                                              float* __restrict__ Cs) {
    for (int p = blockIdx.x * 256 + threadIdx.x; p < E; p += gridDim.x * 256) {
        int e = order[p];
        srcs[p] = eidx[e];
        dsts[p] = eidx[E + e];
        Cs[p] = 0.5f * (cosf(ew[e] * PIC) + 1.0f);
    }
}

// ---------------- weight packs: frag-ready bf16 hi/lo ----------------
// layout idx = ((ks*4+g)*64 + f)*8 + j  -> element B[k=ks*32+g*8+j][n=f]
__global__ __launch_bounds__(256) void k_pack(const float* __restrict__ W1,
                                              const float* __restrict__ W2,
                                              ushort* __restrict__ wpk) {
    int l = blockIdx.x;
    ushort* o = wpk + l * 16384;
    for (int idx = threadIdx.x; idx < 4096; idx += 256) {
        int j = idx & 7, f = (idx >> 3) & 63, g = (idx >> 9) & 3, ks = idx >> 11;
        int k = ks * 32 + g * 8 + j;
        float v1 = (k < 50) ? W1[l * 3200 + f * 50 + k] : 0.f;
        ushort h1 = bf16rne(v1);
        o[idx] = h1;
        o[4096 + idx] = bf16rne(v1 - bf2f(h1));
        float v2 = W2[l * 4096 + f * 64 + k];
        ushort h2 = bf16rne(v2);
        o[8192 + idx] = h2;
        o[12288 + idx] = bf16rne(v2 - bf2f(h2));
    }
}

// ---------------- pre FC: out = relu(x @ pre_W^T + pre_b) ----------------
__global__ __launch_bounds__(256) void k_pre(const float* __restrict__ x,
                                             const float* __restrict__ W,
                                             const float* __restrict__ b,
                                             float* __restrict__ out) {
    __shared__ float WT[92 * 64];
    __shared__ float xs[4 * 92];
    __shared__ float bs[64];
    for (int i = threadIdx.x; i < 92 * 64; i += 256) {
        int f = i / 92, k = i - f * 92;
        WT[k * 64 + f] = W[i];
    }
    if (threadIdx.x < 64) bs[threadIdx.x] = b[threadIdx.x];
    __syncthreads();
    int f = threadIdx.x & 63, nl = threadIdx.x >> 6;
    for (int g0 = blockIdx.x; g0 < N / 4; g0 += gridDim.x) {
        int n0 = g0 * 4;
        for (int i = threadIdx.x; i < 4 * 92; i += 256) xs[i] = x[(size_t)n0 * 92 + i];
        __syncthreads();
        float acc = bs[f];
        #pragma unroll 4
        for (int k = 0; k < 92; k++) acc = fmaf(xs[nl * 92 + k], WT[k * 64 + f], acc);
        out[(size_t)(n0 + nl) * 64 + f] = fmaxf(acc, 0.f);
        __syncthreads();
    }
}

// ---------------- h = BN(out) @ cf_W1^T, optionally applying BN in place ----------------
__global__ __launch_bounds__(256) void k_h(float* __restrict__ out,
                                           const float* __restrict__ W,
                                           const float* __restrict__ bnacc,
                                           int useBN,
                                           float* __restrict__ h) {
    __shared__ float WT[64 * 64];
    __shared__ float xs[4 * 64];
    int t = threadIdx.x;
    for (int i = t; i < 4096; i += 256) {
        int f = i >> 6, j = i & 63;
        WT[j * 64 + f] = W[i];
    }
    float4 sc = make_float4(1.f, 1.f, 1.f, 1.f);
    float4 sh = make_float4(0.f, 0.f, 0.f, 0.f);
    if (t < 64 && useBN) {
        sc = ((const float4*)(bnacc + 128))[t & 15];
        sh = ((const float4*)(bnacc + 192))[t & 15];
    }
    __syncthreads();
    int f = t & 63, nl = t >> 6;
    for (int g0 = blockIdx.x; g0 < N / 4; g0 += gridDim.x) {
        int n0 = g0 * 4;
        if (t < 64) {
            float4 v = ((const float4*)(out + (size_t)n0 * 64))[t];
            v.x = fmaf(v.x, sc.x, sh.x);
            v.y = fmaf(v.y, sc.y, sh.y);
            v.z = fmaf(v.z, sc.z, sh.z);
            v.w = fmaf(v.w, sc.w, sh.w);
            ((float4*)xs)[t] = v;
            if (useBN) ((float4*)(out + (size_t)n0 * 64))[t] = v;
        }
        __syncthreads();
        float acc = 0.f;
        #pragma unroll 4
        for (int j = 0; j < 64; j++) acc = fmaf(xs[nl * 64 + j], WT[j * 64 + f], acc);
        h[(size_t)(n0 + nl) * 64 + f] = acc;
        __syncthreads();
    }
}

// ---------------- fused edge kernel: MFMA bf16x3, dst-sorted ----------------
__global__ __launch_bounds__(256, 2) void k_edge(const float* __restrict__ ea,
                                                 const int* __restrict__ order,
                                                 const int* __restrict__ srcs,
                                                 const int* __restrict__ dsts,
                                                 const float* __restrict__ Cs,
                                                 const float* __restrict__ h,
                                                 float* __restrict__ agg,
                                                 const ushort* __restrict__ wpk_l,
                                                 const float* __restrict__ b1,
                                                 const float* __restrict__ b2) {
    __shared__ ushort eaH[64 * 64], eaL[64 * 64];   // swizzled 16B chunks in 128B rows
    __shared__ ushort t1H[64 * 64], t1L[64 * 64];
    __shared__ float  bufB[64 * 68];
    __shared__ int   srcM[2][64];
    __shared__ int   dstM[2][64];
    __shared__ float cM[2][64];

    const int t = threadIdx.x;
    const int w = t >> 6, l = t & 63;
    const int lm = l & 15, lg = l >> 4;

    // register-resident B fragments (hi/lo), loaded once (L2-hot)
    s8 b1h[4][2], b1l[4][2], b2h[4][2], b2l[4][2];
    #pragma unroll
    for (int ft = 0; ft < 4; ft++)
        #pragma unroll
        for (int ks = 0; ks < 2; ks++) {
            int idx = ((ks * 4 + lg) * 64 + ft * 16 + lm) * 8;
            b1h[ft][ks] = *(const s8*)(wpk_l + idx);
            b1l[ft][ks] = *(const s8*)(wpk_l + 4096 + idx);
            b2h[ft][ks] = *(const s8*)(wpk_l + 8192 + idx);
            b2l[ft][ks] = *(const s8*)(wpk_l + 12288 + idx);
        }
    float b1v[4], b2v[4];
    #pragma unroll
    for (int ft = 0; ft < 4; ft++) { b1v[ft] = b1[ft * 16 + lm]; b2v[ft] = b2[ft * 16 + lm]; }

    const int gstride = gridDim.x;
    const int se = t & 63;        // staged edge row
    const int sq = t >> 6;        // staged k-quarter (16 floats)
    const int e4 = (t & 15) * 4, f4 = (t >> 4) * 4;

    // ---- prologue: stage tile0 ----
    {
        int e0 = blockIdx.x * 64;
        int ord = order[e0 + se];
        const float* row = ea + (size_t)ord * 50;
        float pv[16];
        if (sq < 3) {
            #pragma unroll
            for (int i = 0; i < 8; i++) {
                float2 v = *(const float2*)(row + sq * 16 + i * 2);
                pv[2 * i] = v.x; pv[2 * i + 1] = v.y;
            }
        } else {
            float2 v = *(const float2*)(row + 48);
            pv[0] = v.x; pv[1] = v.y;
            #pragma unroll
            for (int i = 2; i < 16; i++) pv[i] = 0.f;
        }
        #pragma unroll
        for (int c2 = 0; c2 < 2; c2++) {
            int swz = (sq * 2 + c2) ^ (se & 7);
            s8 hi, lo;
            #pragma unroll
            for (int j = 0; j < 8; j++) {
                float x = pv[c2 * 8 + j];
                ushort hh = bf16rne(x);
                hi[j] = (short)hh;
                lo[j] = (short)bf16rne(x - bf2f(hh));
            }
            *(s8*)&eaH[se * 64 + swz * 8] = hi;
            *(s8*)&eaL[se * 64 + swz * 8] = lo;
        }
        if (t < 64) srcM[0][t] = srcs[e0 + t];
        else if (t < 128) dstM[0][t - 64] = dsts[e0 + (t - 64)];
        else if (t < 192) cM[0][t - 128] = Cs[e0 + (t - 128)];
    }
    __syncthreads();

    int it = 0;
    for (int tile = blockIdx.x; tile < TILES; tile += gstride, it ^= 1) {
        const int cur = it, nxtb = it ^ 1;
        int ntile = tile + gstride;
        int en0 = (ntile < TILES ? ntile : tile) * 64;

        // ---- issue next-tile prefetch into registers ----
        float pv[16];
        {
            int ord = order[en0 + se];
            const float* row = ea + (size_t)ord * 50;
            if (sq < 3) {
                #pragma unroll
                for (int i = 0; i < 8; i++) {
                    float2 v = *(const float2*)(row + sq * 16 + i * 2);
                    pv[2 * i] = v.x; pv[2 * i + 1] = v.y;
                }
            } else {
                float2 v = *(const float2*)(row + 48);
                pv[0] = v.x; pv[1] = v.y;
                #pragma unroll
                for (int i = 2; i < 16; i++) pv[i] = 0.f;
            }
        }
        int pSrc = 0, pDst = 0; float pC = 0.f;
        if (t < 64) pSrc = srcs[en0 + t];
        else if (t < 128) pDst = dsts[en0 + (t - 64)];
        else if (t < 192) pC = Cs[en0 + (t - 128)];

        // ---- GEMM1: z1 = ea @ W1pack + b1 (bf16x3) ----
        const int erow = w * 16 + lm;
        f32x4 acc[4];
        #pragma unroll
        for (int ft = 0; ft < 4; ft++) acc[ft] = (f32x4){b1v[ft], b1v[ft], b1v[ft], b1v[ft]};
        #pragma unroll
        for (int ks = 0; ks < 2; ks++) {
            int swz = (ks * 4 + lg) ^ (erow & 7);
            s8 ah = *(const s8*)&eaH[erow * 64 + swz * 8];
            s8 al = *(const s8*)&eaL[erow * 64 + swz * 8];
            #pragma unroll
            for (int ft = 0; ft < 4; ft++) {
                acc[ft] = __builtin_amdgcn_mfma_f32_16x16x32_bf16(ah, b1h[ft][ks], acc[ft], 0, 0, 0);
                acc[ft] = __builtin_amdgcn_mfma_f32_16x16x32_bf16(ah, b1l[ft][ks], acc[ft], 0, 0, 0);
                acc[ft] = __builtin_amdgcn_mfma_f32_16x16x32_bf16(al, b1h[ft][ks], acc[ft], 0, 0, 0);
            }
        }
        // ssp + hi/lo split -> t1 LDS
        #pragma unroll
        for (int ft = 0; ft < 4; ft++) {
            int k = ft * 16 + lm;
            int cbase = k >> 3;
            #pragma unroll
            for (int r = 0; r < 4; r++) {
                int eR = w * 16 + lg * 4 + r;
                float v = sspf(acc[ft][r]);
                ushort hh = bf16rne(v);
                ushort ll = bf16rne(v - bf2f(hh));
                int idx = eR * 64 + ((cbase ^ (eR & 7)) << 3) + (k & 7);
                t1H[idx] = hh;
                t1L[idx] = ll;
            }
        }
        __syncthreads();   // bar1: t1 ready; eaH consumed by all waves

        // ---- write prefetched ea + meta into LDS ----
        #pragma unroll
        for (int c2 = 0; c2 < 2; c2++) {
            int swz = (sq * 2 + c2) ^ (se & 7);
            s8 hi, lo;
            #pragma unroll
            for (int j = 0; j < 8; j++) {
                float x = pv[c2 * 8 + j];
                ushort hh = bf16rne(x);
                hi[j] = (short)hh;
                lo[j] = (short)bf16rne(x - bf2f(hh));
            }
            *(s8*)&eaH[se * 64 + swz * 8] = hi;
            *(s8*)&eaL[se * 64 + swz * 8] = lo;
        }
        if (t < 64) srcM[nxtb][t] = pSrc;
        else if (t < 128) dstM[nxtb][t - 64] = pDst;
        else if (t < 192) cM[nxtb][t - 128] = pC;

        // ---- GEMM2: Wf = t1 @ W2pack + b2 (bf16x3) ----
        f32x4 acc2[4];
        #pragma unroll
        for (int ft = 0; ft < 4; ft++) acc2[ft] = (f32x4){b2v[ft], b2v[ft], b2v[ft], b2v[ft]};
        #pragma unroll
        for (int ks = 0; ks < 2; ks++) {
            int swz = (ks * 4 + lg) ^ (erow & 7);
            s8 ah = *(const s8*)&t1H[erow * 64 + swz * 8];
            s8 al = *(const s8*)&t1L[erow * 64 + swz * 8];
            #pragma unroll
            for (int ft = 0; ft < 4; ft++) {
                acc2[ft] = __builtin_amdgcn_mfma_f32_16x16x32_bf16(ah, b2h[ft][ks], acc2[ft], 0, 0, 0);
                acc2[ft] = __builtin_amdgcn_mfma_f32_16x16x32_bf16(ah, b2l[ft][ks], acc2[ft], 0, 0, 0);
                acc2[ft] = __builtin_amdgcn_mfma_f32_16x16x32_bf16(al, b2h[ft][ks], acc2[ft], 0, 0, 0);
            }
        }
        // ---- modulate by C, write Wf*C to bufB ----
        float cv[4];
        #pragma unroll
        for (int r = 0; r < 4; r++) cv[r] = cM[cur][w * 16 + lg * 4 + r];
        #pragma unroll
        for (int ft = 0; ft < 4; ft++) {
            int f = ft * 16 + lm;
            #pragma unroll
            for (int r = 0; r < 4; r++) {
                int eR = w * 16 + lg * 4 + r;
                bufB[eR * 68 + f] = acc2[ft][r] * cv[r];
            }
        }
        __syncthreads();   // bar2: bufB(Wf*C) + next ea/meta ready

        // ---- h-mult pass: bufB[e][f] *= h[src[e]][f] ----
        {
            int s0 = srcM[cur][e4 + 0], s1 = srcM[cur][e4 + 1];
            int s2 = srcM[cur][e4 + 2], s3 = srcM[cur][e4 + 3];
            float4 h0 = *(const float4*)&h[(size_t)s0 * 64 + f4];
            float4 h1 = *(const float4*)&h[(size_t)s1 * 64 + f4];
            float4 h2 = *(const float4*)&h[(size_t)s2 * 64 + f4];
            float4 h3 = *(const float4*)&h[(size_t)s3 * 64 + f4];
            float4* p0 = (float4*)&bufB[(e4 + 0) * 68 + f4];
            float4* p1 = (float4*)&bufB[(e4 + 1) * 68 + f4];
            float4* p2 = (float4*)&bufB[(e4 + 2) * 68 + f4];
            float4* p3 = (float4*)&bufB[(e4 + 3) * 68 + f4];
            float4 m0 = *p0, m1 = *p1, m2 = *p2, m3 = *p3;
            m0.x *= h0.x; m0.y *= h0.y; m0.z *= h0.z; m0.w *= h0.w;
            m1.x *= h1.x; m1.y *= h1.y; m1.z *= h1.z; m1.w *= h1.w;
            m2.x *= h2.x; m2.y *= h2.y; m2.z *= h2.z; m2.w *= h2.w;
            m3.x *= h3.x; m3.y *= h3.y; m3.z *= h3.z; m3.w *= h3.w;
            *p0 = m0; *p1 = m1; *p2 = m2; *p3 = m3;
        }
        __syncthreads();   // bar3: messages complete

        // ---- segmented reduce per dst-run ----
        #pragma unroll
        for (int i = 0; i < 4; i++) {
            int e = e4 + i;
            int d = dstM[cur][e];
            if (e > 0 && dstM[cur][e - 1] == d) continue;
            int end = e + 1;
            while (end < 64 && dstM[cur][end] == d) end++;
            float4 s = *(const float4*)&bufB[e * 68 + f4];
            for (int r = e + 1; r < end; r++) {
                float4 v = *(const float4*)&bufB[r * 68 + f4];
                s.x += v.x; s.y += v.y; s.z += v.z; s.w += v.w;
            }
            float* ap = agg + (size_t)d * 64 + f4;
            if (e > 0 && end < 64) {
                *(float4*)ap = s;
            } else {
                uadd(ap + 0, s.x); uadd(ap + 1, s.y);
                uadd(ap + 2, s.z); uadd(ap + 3, s.w);
            }
        }
        // no barrier needed: next-iter writes are ordered by bar1(t+1)
    }
}

// ---------------- interaction tail + residual + BN stats ----------------
__global__ __launch_bounds__(256) void k_post(const float* __restrict__ agg,
                                              const float* __restrict__ W2c,
                                              const float* __restrict__ b2c,
                                              const float* __restrict__ Wi,
                                              const float* __restrict__ bi,
                                              float* __restrict__ out,
                                              float* __restrict__ bnacc) {
    __shared__ float w2T[64 * 64];
    __shared__ float wiT[64 * 64];
    __shared__ float aL[16 * 64];
    __shared__ float sL[16 * 64];
    __shared__ float b2s[64], bis[64];
    int t = threadIdx.x;
    for (int i = t; i < 4096; i += 256) {
        int f = i >> 6, j = i & 63;
        w2T[j * 64 + f] = W2c[i];
        wiT[j * 64 + f] = Wi[i];
    }
    if (t < 64) { b2s[t] = b2c[t]; bis[t] = bi[t]; }
    __syncthreads();
    const int nl = t >> 4;
    const int f4 = (t & 15) * 4;
    for (int g0 = blockIdx.x; g0 < N / 16; g0 += gridDim.x) {
        int n0 = g0 * 16;
        ((float4*)aL)[t] = ((const float4*)(agg + (size_t)n0 * 64))[t];
        __syncthreads();
        float s[4] = {b2s[f4], b2s[f4 + 1], b2s[f4 + 2], b2s[f4 + 3]};
        #pragma unroll 4
        for (int j = 0; j < 64; j++) {
            float av = aL[nl * 64 + j];
            float4 wv = *(const float4*)&w2T[j * 64 + f4];
            s[0] = fmaf(av, wv.x, s[0]);
            s[1] = fmaf(av, wv.y, s[1]);
            s[2] = fmaf(av, wv.z, s[2]);
            s[3] = fmaf(av, wv.w, s[3]);
        }
        #pragma unroll
        for (int j = 0; j < 4; j++) s[j] = sspf(s[j]);
        *(float4*)&sL[nl * 64 + f4] = make_float4(s[0], s[1], s[2], s[3]);
        __syncthreads();
        float h2[4] = {bis[f4], bis[f4 + 1], bis[f4 + 2], bis[f4 + 3]};
        #pragma unroll 4
        for (int j = 0; j < 64; j++) {
            float sv = sL[nl * 64 + j];
            float4 wv = *(const float4*)&wiT[j * 64 + f4];
            h2[0] = fmaf(sv, wv.x, h2[0]);
            h2[1] = fmaf(sv, wv.y, h2[1]);
            h2[2] = fmaf(sv, wv.z, h2[2]);
            h2[3] = fmaf(sv, wv.w, h2[3]);
        }
        float4 ov = *(const float4*)&out[(size_t)(n0 + nl) * 64 + f4];
        ov.x += h2[0]; ov.y += h2[1]; ov.z += h2[2]; ov.w += h2[3];
        *(float4*)&out[(size_t)(n0 + nl) * 64 + f4] = ov;
        *(float4*)&aL[nl * 64 + f4] = ov;
        __syncthreads();
        if (t < 64) {
            float sm = 0.f, s2 = 0.f;
            #pragma unroll 4
            for (int n = 0; n < 16; n++) {
                float v = aL[n * 64 + t];
                sm += v;
                s2 = fmaf(v, v, s2);
            }
            uadd(bnacc + t, sm);
            uadd(bnacc + 64 + t, s2);
        }
        __syncthreads();
    }
}

// ---------------- BN finalize: scale/shift ----------------
__global__ void k_bnfin(float* bnacc, const float* __restrict__ g, const float* __restrict__ b) {
    int f = threadIdx.x;
    double mu = (double)bnacc[f] / (double)N;
    double var = (double)bnacc[64 + f] / (double)N - mu * mu;
    double inv = 1.0 / sqrt(var + 1e-5);
    double sc = (double)g[f] * inv;
    bnacc[128 + f] = (float)sc;
    bnacc[192 + f] = (float)((double)b[f] - mu * sc);
}

// ---------------- graph mean-pool with fused final BN ----------------
__global__ __launch_bounds__(256) void k_pool(const float* __restrict__ out,
                                              const int* __restrict__ batch,
                                              const float* __restrict__ bnacc,
                                              float* __restrict__ psum,
                                              float* __restrict__ pcnt) {
    int t = threadIdx.x;
    int q = blockIdx.x * 16 + (t >> 4);
    if (q >= N / 4) return;
    int c = t & 15;
    float4 sc = ((const float4*)(bnacc + 128))[c];
    float4 sh = ((const float4*)(bnacc + 192))[c];
    int n0 = q * 4;
    int gprev = batch[n0];
    float4 acc = {0.f, 0.f, 0.f, 0.f};
    float cnt = 0.f;
    for (int i = 0; i < 4; i++) {
        int n = n0 + i;
        int gb = batch[n];
        float4 v = ((const float4*)(out + (size_t)n * 64))[c];
        v.x = fmaf(v.x, sc.x, sh.x);
        v.y = fmaf(v.y, sc.y, sh.y);
        v.z = fmaf(v.z, sc.z, sh.z);
        v.w = fmaf(v.w, sc.w, sh.w);
        if (gb != gprev) {
            float* p = psum + (size_t)gprev * 64 + c * 4;
            uadd(p + 0, acc.x); uadd(p + 1, acc.y); uadd(p + 2, acc.z); uadd(p + 3, acc.w);
            if (c == 0) uadd(pcnt + gprev, cnt);
            acc = make_float4(0.f, 0.f, 0.f, 0.f);
            cnt = 0.f;
            gprev = gb;
        }
        acc.x += v.x; acc.y += v.y; acc.z += v.z; acc.w += v.w;
        cnt += 1.f;
    }
    float* p = psum + (size_t)gprev * 64 + c * 4;
    uadd(p + 0, acc.x); uadd(p + 1, acc.y); uadd(p + 2, acc.z); uadd(p + 3, acc.w);
    if (c == 0) uadd(pcnt + gprev, cnt);
}

// ---------------- head: mean, post FC + relu, out FC ----------------
__global__ __launch_bounds__(256) void k_head(const float* __restrict__ psum,
                                              const float* __restrict__ pcnt,
                                              const float* __restrict__ pW,
                                              const float* __restrict__ pb,
                                              const float* __restrict__ oW,
                                              const float* __restrict__ ob,
                                              float* __restrict__ y) {
    __shared__ float pl[4][64];
    int t = threadIdx.x;
    int gl = t >> 6, f = t & 63;
    int g = blockIdx.x * 4 + gl;
    float cnt = fmaxf(pcnt[g], 1.f);
    pl[gl][f] = psum[(size_t)g * 64 + f] / cnt;
    __syncthreads();
    float acc = pb[f];
    #pragma unroll 4
    for (int j = 0; j < 64; j++) acc = fmaf(pl[gl][j], pW[f * 64 + j], acc);
    float hh = fmaxf(acc, 0.f);
    float part = hh * oW[f];
    #pragma unroll
    for (int off = 32; off; off >>= 1) part += __shfl_xor(part, off);
    if (f == 0) y[g] = part + ob[0];
}

extern "C" void kernel_launch(void* const* d_in, const int* in_sizes, int n_in,
                              void* d_out, int out_size, void* d_ws, size_t ws_size,
                              hipStream_t stream) {
    const float* x      = (const float*)d_in[0];
    const float* ew     = (const float*)d_in[1];
    const float* ea     = (const float*)d_in[2];
    const int*   eidx   = (const int*)d_in[3];
    const int*   batch  = (const int*)d_in[4];
    const float* pre_W  = (const float*)d_in[5];
    const float* pre_b  = (const float*)d_in[6];
    const float* mlp_W1 = (const float*)d_in[7];
    const float* mlp_b1 = (const float*)d_in[8];
    const float* mlp_W2 = (const float*)d_in[9];
    const float* mlp_b2 = (const float*)d_in[10];
    const float* cf_W1  = (const float*)d_in[11];
    const float* cf_W2  = (const float*)d_in[12];
    const float* cf_b2  = (const float*)d_in[13];
    const float* int_W  = (const float*)d_in[14];
    const float* int_b  = (const float*)d_in[15];
    const float* bn_g   = (const float*)d_in[16];
    const float* bn_b   = (const float*)d_in[17];
    const float* post_W = (const float*)d_in[18];
    const float* post_b = (const float*)d_in[19];
    const float* out_W  = (const float*)d_in[20];
    const float* out_b  = (const float*)d_in[21];

    float* ws    = (float*)d_ws;
    float* outb  = ws;                              // N*64
    float* hb    = ws + (size_t)N * 64;             // N*64
    float* aggb  = ws + (size_t)2 * N * 64;         // N*64
    float* bnacc = ws + (size_t)3 * N * 64;         // 256
    float* psum  = bnacc + 256;                     // G*64
    float* pcnt  = psum + (size_t)G * 64;           // G
    int*   cnt   = (int*)(pcnt + G);                // N
    int*   curs  = cnt + N;                         // N
    int*   order = curs + N;                        // E
    int*   srcs  = order + E;                       // E
    int*   dsts  = srcs + E;                        // E
    float* Csrt  = (float*)(dsts + E);              // E
    ushort* wpk  = (ushort*)(Csrt + E);             // 3*16384

    // ---- counting sort of edges by dst + sorted meta + weight packs ----
    hipMemsetAsync(cnt, 0, (size_t)N * sizeof(int), stream);
    k_hist<<<1024, 256, 0, stream>>>(eidx, cnt);
    k_scan<<<1, 1024, 0, stream>>>(cnt, curs);
    k_scatter<<<2048, 256, 0, stream>>>(eidx, curs, order);
    k_meta<<<2048, 256, 0, stream>>>(eidx, ew, order, srcs, dsts, Csrt);
    k_pack<<<3, 256, 0, stream>>>(mlp_W1, mlp_W2, wpk);

    k_pre<<<1024, 256, 0, stream>>>(x, pre_W, pre_b, outb);

    for (int l = 0; l < 3; l++) {
        hipMemsetAsync(aggb, 0, (size_t)N * 64 * sizeof(float), stream);
        k_h<<<1024, 256, 0, stream>>>(outb, cf_W1 + l * 4096, bnacc, l > 0 ? 1 : 0, hb);
        hipMemsetAsync(bnacc, 0, 128 * sizeof(float), stream);
        k_edge<<<512, 256, 0, stream>>>(ea, order, srcs, dsts, Csrt, hb, aggb,
                                        wpk + l * 16384, mlp_b1 + l * 64, mlp_b2 + l * 64);
        k_post<<<1024, 256, 0, stream>>>(aggb, cf_W2 + l * 4096, cf_b2 + l * 64,
                                         int_W + l * 4096, int_b + l * 64, outb, bnacc);
        k_bnfin<<<1, 64, 0, stream>>>(bnacc, bn_g + l * 64, bn_b + l * 64);
    }

    hipMemsetAsync(psum, 0, (size_t)(G * 64 + G) * sizeof(float), stream);
    k_pool<<<(N / 4 + 15) / 16, 256, 0, stream>>>(outb, batch, bnacc, psum, pcnt);
    k_head<<<G / 4, 256, 0, stream>>>(psum, pcnt, post_W, post_b, out_W, out_b, (float*)d_out);
}

// Round 5
// 2177.922 us; speedup vs baseline: 1.2743x; 1.2743x over previous
//
#include <hip/hip_runtime.h>

constexpr int N = 50000;
constexpr int E = 1200000;
constexpr int G = 512;
constexpr int TILES = E / 64;        // 18750 exactly
constexpr float LOG2_ = 0.69314718055994531f;
constexpr float PIC = 0.39269908169872414f;   // pi / 8.0

typedef __attribute__((ext_vector_type(8))) short s8;     // 8 bf16 (4 VGPR)
typedef __attribute__((ext_vector_type(4))) float f32x4;  // MFMA acc

__device__ __forceinline__ float sspf(float x) {
    return fmaxf(x, 0.f) + __logf(1.f + __expf(-fabsf(x))) - LOG2_;
}
__device__ __forceinline__ void uadd(float* p, float v) { unsafeAtomicAdd(p, v); }
__device__ __forceinline__ ushort bf16rne(float x) {
    unsigned u = __float_as_uint(x);
    return (ushort)((u + 0x7FFFu + ((u >> 16) & 1u)) >> 16);
}
__device__ __forceinline__ float bf2f(ushort h) {
    return __uint_as_float(((unsigned)h) << 16);
}

// ---------------- sort stage 1: histogram of dst ----------------
__global__ __launch_bounds__(256) void k_hist(const int* __restrict__ eidx,
                                              int* __restrict__ cnt) {
    for (int e = blockIdx.x * 256 + threadIdx.x; e < E; e += gridDim.x * 256)
        atomicAdd(cnt + eidx[E + e], 1);
}

// ---------------- sort stage 2: exclusive scan -> cursor ----------------
__global__ __launch_bounds__(1024) void k_scan(const int* __restrict__ cnt,
                                               int* __restrict__ cursor) {
    __shared__ int part[1024];
    const int CH = 49;
    int t = threadIdx.x;
    int b = t * CH;
    int s = 0;
    for (int i = 0; i < CH; i++) { int idx = b + i; if (idx < N) s += cnt[idx]; }
    part[t] = s;
    __syncthreads();
    for (int off = 1; off < 1024; off <<= 1) {
        int add = (t >= off) ? part[t - off] : 0;
        int v = part[t];
        __syncthreads();
        part[t] = v + add;
        __syncthreads();
    }
    int excl = (t == 0) ? 0 : part[t - 1];
    for (int i = 0; i < CH; i++) {
        int idx = b + i;
        if (idx < N) { cursor[idx] = excl; excl += cnt[idx]; }
    }
}

// ---------------- sort stage 3: order[p]=e and rank[e]=p ----------------
__global__ __launch_bounds__(256) void k_scatter(const int* __restrict__ eidx,
                                                 int* __restrict__ cursor,
                                                 int* __restrict__ order,
                                                 int* __restrict__ rank) {
    for (int e = blockIdx.x * 256 + threadIdx.x; e < E; e += gridDim.x * 256) {
        int d = eidx[E + e];
        int p = atomicAdd(cursor + d, 1);
        order[p] = e;
        rank[e] = p;
    }
}

// ---------------- sorted meta arrays (coalesced reads, scatter writes) -----
__global__ __launch_bounds__(256) void k_meta(const int* __restrict__ eidx,
                                              const float* __restrict__ ew,
                                              const int* __restrict__ rank,
                                              int* __restrict__ srcs,
                                              int* __restrict__ dsts,
                                              float* __restrict__ Cs) {
    for (int e = blockIdx.x * 256 + threadIdx.x; e < E; e += gridDim.x * 256) {
        int p = rank[e];
        srcs[p] = eidx[e];
        dsts[p] = eidx[E + e];
        Cs[p] = 0.5f * (cosf(ew[e] * PIC) + 1.0f);
    }
}

// ---------------- weight packs: frag-ready bf16 hi/lo ----------------
// layout idx = ((ks*4+g)*64 + f)*8 + j  -> element B[k=ks*32+g*8+j][n=f]
__global__ __launch_bounds__(256) void k_pack(const float* __restrict__ W1,
                                              const float* __restrict__ W2,
                                              ushort* __restrict__ wpk) {
    int l = blockIdx.x;
    ushort* o = wpk + l * 16384;
    for (int idx = threadIdx.x; idx < 4096; idx += 256) {
        int j = idx & 7, f = (idx >> 3) & 63, g = (idx >> 9) & 3, ks = idx >> 11;
        int k = ks * 32 + g * 8 + j;
        float v1 = (k < 50) ? W1[l * 3200 + f * 50 + k] : 0.f;
        ushort h1 = bf16rne(v1);
        o[idx] = h1;
        o[4096 + idx] = bf16rne(v1 - bf2f(h1));
        float v2 = W2[l * 4096 + f * 64 + k];
        ushort h2 = bf16rne(v2);
        o[8192 + idx] = h2;
        o[12288 + idx] = bf16rne(v2 - bf2f(h2));
    }
}

// ---------------- pre FC: out = relu(x @ pre_W^T + pre_b) ----------------
__global__ __launch_bounds__(256) void k_pre(const float* __restrict__ x,
                                             const float* __restrict__ W,
                                             const float* __restrict__ b,
                                             float* __restrict__ out) {
    __shared__ float WT[92 * 64];
    __shared__ float xs[4 * 92];
    __shared__ float bs[64];
    for (int i = threadIdx.x; i < 92 * 64; i += 256) {
        int f = i / 92, k = i - f * 92;
        WT[k * 64 + f] = W[i];
    }
    if (threadIdx.x < 64) bs[threadIdx.x] = b[threadIdx.x];
    __syncthreads();
    int f = threadIdx.x & 63, nl = threadIdx.x >> 6;
    for (int g0 = blockIdx.x; g0 < N / 4; g0 += gridDim.x) {
        int n0 = g0 * 4;
        for (int i = threadIdx.x; i < 4 * 92; i += 256) xs[i] = x[(size_t)n0 * 92 + i];
        __syncthreads();
        float acc = bs[f];
        #pragma unroll 4
        for (int k = 0; k < 92; k++) acc = fmaf(xs[nl * 92 + k], WT[k * 64 + f], acc);
        out[(size_t)(n0 + nl) * 64 + f] = fmaxf(acc, 0.f);
        __syncthreads();
    }
}

// ---------------- h = BN(out) @ cf_W1^T, optionally applying BN in place ---
__global__ __launch_bounds__(256) void k_h(float* __restrict__ out,
                                           const float* __restrict__ W,
                                           const float* __restrict__ bnacc,
                                           int useBN,
                                           float* __restrict__ h) {
    __shared__ float WT[64 * 64];
    __shared__ float xs[4 * 64];
    int t = threadIdx.x;
    for (int i = t; i < 4096; i += 256) {
        int f = i >> 6, j = i & 63;
        WT[j * 64 + f] = W[i];
    }
    float4 sc = make_float4(1.f, 1.f, 1.f, 1.f);
    float4 sh = make_float4(0.f, 0.f, 0.f, 0.f);
    if (t < 64 && useBN) {
        sc = ((const float4*)(bnacc + 128))[t & 15];
        sh = ((const float4*)(bnacc + 192))[t & 15];
    }
    __syncthreads();
    int f = t & 63, nl = t >> 6;
    for (int g0 = blockIdx.x; g0 < N / 4; g0 += gridDim.x) {
        int n0 = g0 * 4;
        if (t < 64) {
            float4 v = ((const float4*)(out + (size_t)n0 * 64))[t];
            v.x = fmaf(v.x, sc.x, sh.x);
            v.y = fmaf(v.y, sc.y, sh.y);
            v.z = fmaf(v.z, sc.z, sh.z);
            v.w = fmaf(v.w, sc.w, sh.w);
            ((float4*)xs)[t] = v;
            if (useBN) ((float4*)(out + (size_t)n0 * 64))[t] = v;
        }
        __syncthreads();
        float acc = 0.f;
        #pragma unroll 4
        for (int j = 0; j < 64; j++) acc = fmaf(xs[nl * 64 + j], WT[j * 64 + f], acc);
        h[(size_t)(n0 + nl) * 64 + f] = acc;
        __syncthreads();
    }
}

// ---------------- PATH A phase 1: original-order MFMA filter MLP ----------
// writes Wf*C (fp32) rows to dst-sorted slots via rank[]
__global__ __launch_bounds__(256, 2) void k_edge1(const float* __restrict__ ea,
                                                  const float* __restrict__ ew,
                                                  const int* __restrict__ rank,
                                                  float* __restrict__ wfc,
                                                  const ushort* __restrict__ wpk_l,
                                                  const float* __restrict__ b1,
                                                  const float* __restrict__ b2) {
    __shared__ ushort eaH[4096], eaL[4096];
    __shared__ ushort t1H[4096], t1L[4096];
    __shared__ float  bufB[64 * 68];

    const int t = threadIdx.x;
    const int w = t >> 6, l = t & 63;
    const int lm = l & 15, lg = l >> 4;
    const int se = t & 63, sq = t >> 6;
    const int e4 = (t & 15) * 4, f4 = (t >> 4) * 4;
    const int erow = w * 16 + lm;

    // register-resident B fragments (hi/lo) — R3-proven layout
    s8 b1h[4][2], b1l[4][2], b2h[4][2], b2l[4][2];
    #pragma unroll
    for (int ft = 0; ft < 4; ft++)
        #pragma unroll
        for (int ks = 0; ks < 2; ks++) {
            int idx = ((ks * 4 + lg) * 64 + ft * 16 + lm) * 8;
            b1h[ft][ks] = *(const s8*)(wpk_l + idx);
            b1l[ft][ks] = *(const s8*)(wpk_l + 4096 + idx);
            b2h[ft][ks] = *(const s8*)(wpk_l + 8192 + idx);
            b2l[ft][ks] = *(const s8*)(wpk_l + 12288 + idx);
        }
    float b1v[4], b2v[4];
    #pragma unroll
    for (int ft = 0; ft < 4; ft++) { b1v[ft] = b1[ft * 16 + lm]; b2v[ft] = b2[ft * 16 + lm]; }

    for (int tile = blockIdx.x; tile < TILES; tile += gridDim.x) {
        const int e0 = tile * 64;
        // ---- load my edge-quarter into registers (coalesced stream) ----
        float pv[16];
        {
            const float* row = ea + (size_t)(e0 + se) * 50;
            if (sq < 3) {
                #pragma unroll
                for (int i = 0; i < 8; i++) {
                    float2 v = *(const float2*)(row + sq * 16 + i * 2);
                    pv[2 * i] = v.x; pv[2 * i + 1] = v.y;
                }
            } else {
                float2 v = *(const float2*)(row + 48);
                pv[0] = v.x; pv[1] = v.y;
                #pragma unroll
                for (int i = 2; i < 16; i++) pv[i] = 0.f;
            }
        }
        float4 ew4 = *(const float4*)&ew[e0 + w * 16 + lg * 4];
        float cvr[4] = {0.5f * (__cosf(ew4.x * PIC) + 1.0f),
                        0.5f * (__cosf(ew4.y * PIC) + 1.0f),
                        0.5f * (__cosf(ew4.z * PIC) + 1.0f),
                        0.5f * (__cosf(ew4.w * PIC) + 1.0f)};
        int4 rk4 = *(const int4*)&rank[e0 + e4];
        __syncthreads();   // previous iteration fully consumed eaH/bufB
        // ---- stage hi/lo swizzled ea ----
        #pragma unroll
        for (int c2 = 0; c2 < 2; c2++) {
            int swz = (sq * 2 + c2) ^ (se & 7);
            s8 hi, lo;
            #pragma unroll
            for (int j = 0; j < 8; j++) {
                float x = pv[c2 * 8 + j];
                ushort hh = bf16rne(x);
                hi[j] = (short)hh;
                lo[j] = (short)bf16rne(x - bf2f(hh));
            }
            *(s8*)&eaH[se * 64 + swz * 8] = hi;
            *(s8*)&eaL[se * 64 + swz * 8] = lo;
        }
        __syncthreads();   // ea tile staged
        // ---- GEMM1: z1 = ea @ W1pack + b1 (bf16x3) ----
        f32x4 acc[4];
        #pragma unroll
        for (int ft = 0; ft < 4; ft++) acc[ft] = (f32x4){b1v[ft], b1v[ft], b1v[ft], b1v[ft]};
        #pragma unroll
        for (int ks = 0; ks < 2; ks++) {
            int swz = (ks * 4 + lg) ^ (erow & 7);
            s8 ah = *(const s8*)&eaH[erow * 64 + swz * 8];
            s8 al = *(const s8*)&eaL[erow * 64 + swz * 8];
            #pragma unroll
            for (int ft = 0; ft < 4; ft++) {
                acc[ft] = __builtin_amdgcn_mfma_f32_16x16x32_bf16(ah, b1h[ft][ks], acc[ft], 0, 0, 0);
                acc[ft] = __builtin_amdgcn_mfma_f32_16x16x32_bf16(ah, b1l[ft][ks], acc[ft], 0, 0, 0);
                acc[ft] = __builtin_amdgcn_mfma_f32_16x16x32_bf16(al, b1h[ft][ks], acc[ft], 0, 0, 0);
            }
        }
        // ---- ssp + hi/lo split -> t1 ----
        #pragma unroll
        for (int ft = 0; ft < 4; ft++) {
            int k = ft * 16 + lm;
            int cbase = k >> 3;
            #pragma unroll
            for (int r = 0; r < 4; r++) {
                int eR = w * 16 + lg * 4 + r;
                float v = sspf(acc[ft][r]);
                ushort hh = bf16rne(v);
                ushort ll = bf16rne(v - bf2f(hh));
                int idx = eR * 64 + ((cbase ^ (eR & 7)) << 3) + (k & 7);
                t1H[idx] = hh;
                t1L[idx] = ll;
            }
        }
        __syncthreads();   // t1 ready
        // ---- GEMM2: Wf = t1 @ W2pack + b2 (bf16x3) ----
        f32x4 acc2[4];
        #pragma unroll
        for (int ft = 0; ft < 4; ft++) acc2[ft] = (f32x4){b2v[ft], b2v[ft], b2v[ft], b2v[ft]};
        #pragma unroll
        for (int ks = 0; ks < 2; ks++) {
            int swz = (ks * 4 + lg) ^ (erow & 7);
            s8 ah = *(const s8*)&t1H[erow * 64 + swz * 8];
            s8 al = *(const s8*)&t1L[erow * 64 + swz * 8];
            #pragma unroll
            for (int ft = 0; ft < 4; ft++) {
                acc2[ft] = __builtin_amdgcn_mfma_f32_16x16x32_bf16(ah, b2h[ft][ks], acc2[ft], 0, 0, 0);
                acc2[ft] = __builtin_amdgcn_mfma_f32_16x16x32_bf16(ah, b2l[ft][ks], acc2[ft], 0, 0, 0);
                acc2[ft] = __builtin_amdgcn_mfma_f32_16x16x32_bf16(al, b2h[ft][ks], acc2[ft], 0, 0, 0);
            }
        }
        // ---- modulate by C -> bufB (e-major fp32) ----
        #pragma unroll
        for (int ft = 0; ft < 4; ft++) {
            int f = ft * 16 + lm;
            #pragma unroll
            for (int r = 0; r < 4; r++) {
                int eR = w * 16 + lg * 4 + r;
                bufB[eR * 68 + f] = acc2[ft][r] * cvr[r];
            }
        }
        __syncthreads();   // bufB ready
        // ---- scatter-store rows to sorted slots ----
        {
            float4 v0 = *(const float4*)&bufB[(e4 + 0) * 68 + f4];
            float4 v1 = *(const float4*)&bufB[(e4 + 1) * 68 + f4];
            float4 v2 = *(const float4*)&bufB[(e4 + 2) * 68 + f4];
            float4 v3 = *(const float4*)&bufB[(e4 + 3) * 68 + f4];
            *(float4*)&wfc[(size_t)rk4.x * 64 + f4] = v0;
            *(float4*)&wfc[(size_t)rk4.y * 64 + f4] = v1;
            *(float4*)&wfc[(size_t)rk4.z * 64 + f4] = v2;
            *(float4*)&wfc[(size_t)rk4.w * 64 + f4] = v3;
        }
    }
}

// ---------------- PATH A phase 2: coalesced msg + segmented reduce --------
__global__ __launch_bounds__(256) void k_edge2(const float* __restrict__ wfc,
                                               const int* __restrict__ srcs,
                                               const int* __restrict__ dsts,
                                               const float* __restrict__ h,
                                               float* __restrict__ agg) {
    __shared__ float bufB[64 * 68];
    __shared__ int dstS[64];
    const int t = threadIdx.x;
    const int e4 = (t & 15) * 4, f4 = (t >> 4) * 4;
    for (int tile = blockIdx.x; tile < TILES; tile += gridDim.x) {
        const int e0 = tile * 64;
        int dreg = 0;
        if (t < 64) dreg = dsts[e0 + t];
        int4 srcv = *(const int4*)&srcs[e0 + e4];
        float4 hv0 = *(const float4*)&h[(size_t)srcv.x * 64 + f4];
        float4 hv1 = *(const float4*)&h[(size_t)srcv.y * 64 + f4];
        float4 hv2 = *(const float4*)&h[(size_t)srcv.z * 64 + f4];
        float4 hv3 = *(const float4*)&h[(size_t)srcv.w * 64 + f4];
        __syncthreads();   // previous reduce done
        // coalesced tile copy wfc -> bufB
        const float4* src4 = (const float4*)(wfc + (size_t)e0 * 64);
        #pragma unroll
        for (int k2 = 0; k2 < 4; k2++) {
            int idx = t + k2 * 256;
            int e = idx >> 4, fq = idx & 15;
            *(float4*)&bufB[e * 68 + fq * 4] = src4[idx];
        }
        if (t < 64) dstS[t] = dreg;
        __syncthreads();
        // h-mult in place
        {
            float4* p0 = (float4*)&bufB[(e4 + 0) * 68 + f4];
            float4* p1 = (float4*)&bufB[(e4 + 1) * 68 + f4];
            float4* p2 = (float4*)&bufB[(e4 + 2) * 68 + f4];
            float4* p3 = (float4*)&bufB[(e4 + 3) * 68 + f4];
            float4 m0 = *p0, m1 = *p1, m2 = *p2, m3 = *p3;
            m0.x *= hv0.x; m0.y *= hv0.y; m0.z *= hv0.z; m0.w *= hv0.w;
            m1.x *= hv1.x; m1.y *= hv1.y; m1.z *= hv1.z; m1.w *= hv1.w;
            m2.x *= hv2.x; m2.y *= hv2.y; m2.z *= hv2.z; m2.w *= hv2.w;
            m3.x *= hv3.x; m3.y *= hv3.y; m3.z *= hv3.z; m3.w *= hv3.w;
            *p0 = m0; *p1 = m1; *p2 = m2; *p3 = m3;
        }
        __syncthreads();
        // segmented reduce per dst-run
        #pragma unroll
        for (int i = 0; i < 4; i++) {
            int e = e4 + i;
            int d = dstS[e];
            if (e > 0 && dstS[e - 1] == d) continue;
            int end = e + 1;
            while (end < 64 && dstS[end] == d) end++;
            float4 s = *(const float4*)&bufB[e * 68 + f4];
            for (int r = e + 1; r < end; r++) {
                float4 v = *(const float4*)&bufB[r * 68 + f4];
                s.x += v.x; s.y += v.y; s.z += v.z; s.w += v.w;
            }
            float* ap = agg + (size_t)d * 64 + f4;
            if (e > 0 && end < 64) {
                *(float4*)ap = s;
            } else {
                uadd(ap + 0, s.x); uadd(ap + 1, s.y);
                uadd(ap + 2, s.z); uadd(ap + 3, s.w);
            }
        }
    }
}

// ---------------- PATH C: R2's fused edge kernel (fp32 VALU, proven) ------
__global__ __launch_bounds__(256) void k_edgeC(const float* __restrict__ ea,
                                               const int* __restrict__ order,
                                               const int* __restrict__ srcs,
                                               const int* __restrict__ dsts,
                                               const float* __restrict__ Cs,
                                               const float* __restrict__ h,
                                               float* __restrict__ agg,
                                               const float* __restrict__ W1,
                                               const float* __restrict__ b1,
                                               const float* __restrict__ W2,
                                               const float* __restrict__ b2) {
    constexpr int BS = 68;
    __shared__ float w1T[50 * 64];
    __shared__ float w2T[64 * 64];
    __shared__ float buf[64 * BS];
    __shared__ float b1s[64], b2s[64], c_s[64];
    __shared__ int src_s[64], dst_s[64], ord_s[64];
    int t = threadIdx.x;
    for (int i = t; i < 3200; i += 256) { int f = i / 50, k = i - f * 50; w1T[k * 64 + f] = W1[i]; }
    for (int i = t; i < 4096; i += 256) { int f = i >> 6, j = i & 63; w2T[j * 64 + f] = W2[i]; }
    if (t < 64) { b1s[t] = b1[t]; b2s[t] = b2[t]; }
    __syncthreads();
    const int e4 = (t & 15) * 4;
    const int f4 = (t >> 4) * 4;
    const int fe = t & 63, kq = t >> 6;
    for (int tile = blockIdx.x; tile < TILES; tile += gridDim.x) {
        const int e0 = tile * 64;
        if (t < 64) {
            ord_s[t] = order[e0 + t];
            src_s[t] = srcs[e0 + t];
            dst_s[t] = dsts[e0 + t];
            c_s[t] = Cs[e0 + t];
        }
        __syncthreads();
        {
            const float2* row2 = (const float2*)ea + (size_t)ord_s[fe] * 25;
            #pragma unroll
            for (int j = 0; j < 24; j += 4) {
                int kp = j + kq;
                float2 v = row2[kp];
                buf[(2 * kp) * BS + fe] = v.x;
                buf[(2 * kp + 1) * BS + fe] = v.y;
            }
            if (kq == 0) {
                float2 v = row2[24];
                buf[48 * BS + fe] = v.x;
                buf[49 * BS + fe] = v.y;
            }
        }
        __syncthreads();
        float a[4][4];
        #pragma unroll
        for (int i = 0; i < 4; i++)
            #pragma unroll
            for (int j = 0; j < 4; j++) a[i][j] = b1s[f4 + j];
        #pragma unroll 2
        for (int k = 0; k < 50; k++) {
            float4 av = *(const float4*)&buf[k * BS + e4];
            float4 wv = *(const float4*)&w1T[k * 64 + f4];
            float avv[4] = {av.x, av.y, av.z, av.w};
            float wvv[4] = {wv.x, wv.y, wv.z, wv.w};
            #pragma unroll
            for (int i = 0; i < 4; i++)
                #pragma unroll
                for (int j = 0; j < 4; j++) a[i][j] = fmaf(avv[i], wvv[j], a[i][j]);
        }
        #pragma unroll
        for (int i = 0; i < 4; i++)
            #pragma unroll
            for (int j = 0; j < 4; j++) a[i][j] = sspf(a[i][j]);
        __syncthreads();
        #pragma unroll
        for (int j = 0; j < 4; j++)
            *(float4*)&buf[(f4 + j) * BS + e4] = make_float4(a[0][j], a[1][j], a[2][j], a[3][j]);
        __syncthreads();
        float w[4][4];
        #pragma unroll
        for (int i = 0; i < 4; i++)
            #pragma unroll
            for (int j = 0; j < 4; j++) w[i][j] = b2s[f4 + j];
        #pragma unroll 2
        for (int k = 0; k < 64; k++) {
            float4 tv = *(const float4*)&buf[k * BS + e4];
            float4 wv = *(const float4*)&w2T[k * 64 + f4];
            float tvv[4] = {tv.x, tv.y, tv.z, tv.w};
            float wvv[4] = {wv.x, wv.y, wv.z, wv.w};
            #pragma unroll
            for (int i = 0; i < 4; i++)
                #pragma unroll
                for (int j = 0; j < 4; j++) w[i][j] = fmaf(tvv[i], wvv[j], w[i][j]);
        }
        float4 m[4];
        #pragma unroll
        for (int i = 0; i < 4; i++) {
            int eg = e4 + i;
            float Cv = c_s[eg];
            float4 hv = *(const float4*)&h[(size_t)src_s[eg] * 64 + f4];
            m[i] = make_float4(hv.x * w[i][0] * Cv, hv.y * w[i][1] * Cv,
                               hv.z * w[i][2] * Cv, hv.w * w[i][3] * Cv);
        }
        __syncthreads();
        #pragma unroll
        for (int i = 0; i < 4; i++)
            *(float4*)&buf[(e4 + i) * BS + f4] = m[i];
        __syncthreads();
        #pragma unroll
        for (int i = 0; i < 4; i++) {
            int e = e4 + i;
            int d = dst_s[e];
            if (e > 0 && dst_s[e - 1] == d) continue;
            int end = e + 1;
            while (end < 64 && dst_s[end] == d) end++;
            float4 s = *(const float4*)&buf[e * BS + f4];
            for (int r = e + 1; r < end; r++) {
                const float4 v = *(const float4*)&buf[r * BS + f4];
                s.x += v.x; s.y += v.y; s.z += v.z; s.w += v.w;
            }
            float* ap = agg + (size_t)d * 64 + f4;
            if (e > 0 && end < 64) {
                *(float4*)ap = s;
            } else {
                uadd(ap + 0, s.x); uadd(ap + 1, s.y);
                uadd(ap + 2, s.z); uadd(ap + 3, s.w);
            }
        }
        __syncthreads();
    }
}

// ---------------- interaction tail + residual + BN stats ----------------
__global__ __launch_bounds__(256) void k_post(const float* __restrict__ agg,
                                              const float* __restrict__ W2c,
                                              const float* __restrict__ b2c,
                                              const float* __restrict__ Wi,
                                              const float* __restrict__ bi,
                                              float* __restrict__ out,
                                              float* __restrict__ bnacc) {
    __shared__ float w2T[64 * 64];
    __shared__ float wiT[64 * 64];
    __shared__ float aL[16 * 64];
    __shared__ float sL[16 * 64];
    __shared__ float b2s[64], bis[64];
    int t = threadIdx.x;
    for (int i = t; i < 4096; i += 256) {
        int f = i >> 6, j = i & 63;
        w2T[j * 64 + f] = W2c[i];
        wiT[j * 64 + f] = Wi[i];
    }
    if (t < 64) { b2s[t] = b2c[t]; bis[t] = bi[t]; }
    __syncthreads();
    const int nl = t >> 4;
    const int f4 = (t & 15) * 4;
    for (int g0 = blockIdx.x; g0 < N / 16; g0 += gridDim.x) {
        int n0 = g0 * 16;
        ((float4*)aL)[t] = ((const float4*)(agg + (size_t)n0 * 64))[t];
        __syncthreads();
        float s[4] = {b2s[f4], b2s[f4 + 1], b2s[f4 + 2], b2s[f4 + 3]};
        #pragma unroll 4
        for (int j = 0; j < 64; j++) {
            float av = aL[nl * 64 + j];
            float4 wv = *(const float4*)&w2T[j * 64 + f4];
            s[0] = fmaf(av, wv.x, s[0]);
            s[1] = fmaf(av, wv.y, s[1]);
            s[2] = fmaf(av, wv.z, s[2]);
            s[3] = fmaf(av, wv.w, s[3]);
        }
        #pragma unroll
        for (int j = 0; j < 4; j++) s[j] = sspf(s[j]);
        *(float4*)&sL[nl * 64 + f4] = make_float4(s[0], s[1], s[2], s[3]);
        __syncthreads();
        float h2[4] = {bis[f4], bis[f4 + 1], bis[f4 + 2], bis[f4 + 3]};
        #pragma unroll 4
        for (int j = 0; j < 64; j++) {
            float sv = sL[nl * 64 + j];
            float4 wv = *(const float4*)&wiT[j * 64 + f4];
            h2[0] = fmaf(sv, wv.x, h2[0]);
            h2[1] = fmaf(sv, wv.y, h2[1]);
            h2[2] = fmaf(sv, wv.z, h2[2]);
            h2[3] = fmaf(sv, wv.w, h2[3]);
        }
        float4 ov = *(const float4*)&out[(size_t)(n0 + nl) * 64 + f4];
        ov.x += h2[0]; ov.y += h2[1]; ov.z += h2[2]; ov.w += h2[3];
        *(float4*)&out[(size_t)(n0 + nl) * 64 + f4] = ov;
        *(float4*)&aL[nl * 64 + f4] = ov;
        __syncthreads();
        if (t < 64) {
            float sm = 0.f, s2 = 0.f;
            #pragma unroll 4
            for (int n = 0; n < 16; n++) {
                float v = aL[n * 64 + t];
                sm += v;
                s2 = fmaf(v, v, s2);
            }
            uadd(bnacc + t, sm);
            uadd(bnacc + 64 + t, s2);
        }
        __syncthreads();
    }
}

// ---------------- BN finalize: scale/shift ----------------
__global__ void k_bnfin(float* bnacc, const float* __restrict__ g, const float* __restrict__ b) {
    int f = threadIdx.x;
    double mu = (double)bnacc[f] / (double)N;
    double var = (double)bnacc[64 + f] / (double)N - mu * mu;
    double inv = 1.0 / sqrt(var + 1e-5);
    double sc = (double)g[f] * inv;
    bnacc[128 + f] = (float)sc;
    bnacc[192 + f] = (float)((double)b[f] - mu * sc);
}

// ---------------- graph mean-pool with fused final BN ----------------
__global__ __launch_bounds__(256) void k_pool(const float* __restrict__ out,
                                              const int* __restrict__ batch,
                                              const float* __restrict__ bnacc,
                                              float* __restrict__ psum,
                                              float* __restrict__ pcnt) {
    int t = threadIdx.x;
    int q = blockIdx.x * 16 + (t >> 4);
    if (q >= N / 4) return;
    int c = t & 15;
    float4 sc = ((const float4*)(bnacc + 128))[c];
    float4 sh = ((const float4*)(bnacc + 192))[c];
    int n0 = q * 4;
    int gprev = batch[n0];
    float4 acc = {0.f, 0.f, 0.f, 0.f};
    float cnt = 0.f;
    for (int i = 0; i < 4; i++) {
        int n = n0 + i;
        int gb = batch[n];
        float4 v = ((const float4*)(out + (size_t)n * 64))[c];
        v.x = fmaf(v.x, sc.x, sh.x);
        v.y = fmaf(v.y, sc.y, sh.y);
        v.z = fmaf(v.z, sc.z, sh.z);
        v.w = fmaf(v.w, sc.w, sh.w);
        if (gb != gprev) {
            float* p = psum + (size_t)gprev * 64 + c * 4;
            uadd(p + 0, acc.x); uadd(p + 1, acc.y); uadd(p + 2, acc.z); uadd(p + 3, acc.w);
            if (c == 0) uadd(pcnt + gprev, cnt);
            acc = make_float4(0.f, 0.f, 0.f, 0.f);
            cnt = 0.f;
            gprev = gb;
        }
        acc.x += v.x; acc.y += v.y; acc.z += v.z; acc.w += v.w;
        cnt += 1.f;
    }
    float* p = psum + (size_t)gprev * 64 + c * 4;
    uadd(p + 0, acc.x); uadd(p + 1, acc.y); uadd(p + 2, acc.z); uadd(p + 3, acc.w);
    if (c == 0) uadd(pcnt + gprev, cnt);
}

// ---------------- head: mean, post FC + relu, out FC ----------------
__global__ __launch_bounds__(256) void k_head(const float* __restrict__ psum,
                                              const float* __restrict__ pcnt,
                                              const float* __restrict__ pW,
                                              const float* __restrict__ pb,
                                              const float* __restrict__ oW,
                                              const float* __restrict__ ob,
                                              float* __restrict__ y) {
    __shared__ float pl[4][64];
    int t = threadIdx.x;
    int gl = t >> 6, f = t & 63;
    int g = blockIdx.x * 4 + gl;
    float cnt = fmaxf(pcnt[g], 1.f);
    pl[gl][f] = psum[(size_t)g * 64 + f] / cnt;
    __syncthreads();
    float acc = pb[f];
    #pragma unroll 4
    for (int j = 0; j < 64; j++) acc = fmaf(pl[gl][j], pW[f * 64 + j], acc);
    float hh = fmaxf(acc, 0.f);
    float part = hh * oW[f];
    #pragma unroll
    for (int off = 32; off; off >>= 1) part += __shfl_xor(part, off);
    if (f == 0) y[g] = part + ob[0];
}

extern "C" void kernel_launch(void* const* d_in, const int* in_sizes, int n_in,
                              void* d_out, int out_size, void* d_ws, size_t ws_size,
                              hipStream_t stream) {
    const float* x      = (const float*)d_in[0];
    const float* ew     = (const float*)d_in[1];
    const float* ea     = (const float*)d_in[2];
    const int*   eidx   = (const int*)d_in[3];
    const int*   batch  = (const int*)d_in[4];
    const float* pre_W  = (const float*)d_in[5];
    const float* pre_b  = (const float*)d_in[6];
    const float* mlp_W1 = (const float*)d_in[7];
    const float* mlp_b1 = (const float*)d_in[8];
    const float* mlp_W2 = (const float*)d_in[9];
    const float* mlp_b2 = (const float*)d_in[10];
    const float* cf_W1  = (const float*)d_in[11];
    const float* cf_W2  = (const float*)d_in[12];
    const float* cf_b2  = (const float*)d_in[13];
    const float* int_W  = (const float*)d_in[14];
    const float* int_b  = (const float*)d_in[15];
    const float* bn_g   = (const float*)d_in[16];
    const float* bn_b   = (const float*)d_in[17];
    const float* post_W = (const float*)d_in[18];
    const float* post_b = (const float*)d_in[19];
    const float* out_W  = (const float*)d_in[20];
    const float* out_b  = (const float*)d_in[21];

    float* ws    = (float*)d_ws;
    float* outb  = ws;                              // N*64
    float* hb    = ws + (size_t)N * 64;             // N*64
    float* aggb  = ws + (size_t)2 * N * 64;         // N*64
    float* bnacc = ws + (size_t)3 * N * 64;         // 256
    float* psum  = bnacc + 256;                     // G*64
    float* pcnt  = psum + (size_t)G * 64;           // G
    int*   cnt   = (int*)(pcnt + G);                // N
    int*   curs  = cnt + N;                         // N
    int*   order = curs + N;                        // E
    int*   rank  = order + E;                       // E
    int*   srcs  = rank + E;                        // E
    int*   dsts  = srcs + E;                        // E
    float* Csrt  = (float*)(dsts + E);              // E
    ushort* wpk  = (ushort*)(Csrt + E);             // 3*16384 ushorts
    float* wfc   = (float*)(wpk + 3 * 16384);       // E*64 (PATH A only)

    size_t needA = (size_t)((char*)wfc - (char*)d_ws) + (size_t)E * 64 * sizeof(float);
    const bool pathA = (ws_size >= needA);

    // ---- sort by dst + meta (+ weight packs for PATH A) ----
    hipMemsetAsync(cnt, 0, (size_t)N * sizeof(int), stream);
    k_hist<<<1024, 256, 0, stream>>>(eidx, cnt);
    k_scan<<<1, 1024, 0, stream>>>(cnt, curs);
    k_scatter<<<2048, 256, 0, stream>>>(eidx, curs, order, rank);
    k_meta<<<2048, 256, 0, stream>>>(eidx, ew, rank, srcs, dsts, Csrt);
    if (pathA) k_pack<<<3, 256, 0, stream>>>(mlp_W1, mlp_W2, wpk);

    k_pre<<<1024, 256, 0, stream>>>(x, pre_W, pre_b, outb);

    for (int l = 0; l < 3; l++) {
        hipMemsetAsync(aggb, 0, (size_t)N * 64 * sizeof(float), stream);
        k_h<<<1024, 256, 0, stream>>>(outb, cf_W1 + l * 4096, bnacc, l > 0 ? 1 : 0, hb);
        hipMemsetAsync(bnacc, 0, 128 * sizeof(float), stream);
        if (pathA) {
            k_edge1<<<1024, 256, 0, stream>>>(ea, ew, rank, wfc,
                                              wpk + l * 16384, mlp_b1 + l * 64, mlp_b2 + l * 64);
            k_edge2<<<2048, 256, 0, stream>>>(wfc, srcs, dsts, hb, aggb);
        } else {
            k_edgeC<<<1536, 256, 0, stream>>>(ea, order, srcs, dsts, Csrt, hb, aggb,
                                              mlp_W1 + l * 3200, mlp_b1 + l * 64,
                                              mlp_W2 + l * 4096, mlp_b2 + l * 64);
        }
        k_post<<<1024, 256, 0, stream>>>(aggb, cf_W2 + l * 4096, cf_b2 + l * 64,
                                         int_W + l * 4096, int_b + l * 64, outb, bnacc);
        k_bnfin<<<1, 64, 0, stream>>>(bnacc, bn_g + l * 64, bn_b + l * 64);
    }

    hipMemsetAsync(psum, 0, (size_t)(G * 64 + G) * sizeof(float), stream);
    k_pool<<<(N / 4 + 15) / 16, 256, 0, stream>>>(outb, batch, bnacc, psum, pcnt);
    k_head<<<G / 4, 256, 0, stream>>>(psum, pcnt, post_W, post_b, out_W, out_b, (float*)d_out);
}